// Round 9
// baseline (144.714 us; speedup 1.0000x reference)
//
#include <hip/hip_runtime.h>
#include <hip/hip_bf16.h>
#include <math.h>

#define BB 2
#define SS 2048
#define HH 16
#define DH 64
#define DQK 128
#define DD (HH*DH)
// Q folded scale = (1/sqrt(128)) * log2(e)  -> scores arrive in log2 domain
#define QS2   0.12751758f
// 8 * log2(e): fixed-max bias in log2 domain (cancels exactly in softmax)
#define EBIAS 11.5415605f

typedef _Float16 half8_t __attribute__((ext_vector_type(8)));
typedef _Float16 half4_t __attribute__((ext_vector_type(4)));
typedef __fp16  fp16x2_t __attribute__((ext_vector_type(2)));   // cvt_pkrtz result
typedef float f32x4_t __attribute__((ext_vector_type(4)));
typedef float f32x4v __attribute__((ext_vector_type(4)));

// Direct hardware trig on REVOLUTIONS (v_sin_f32: D=sin(S0*2pi)).
__device__ __forceinline__ void fsincos(float th, float* sn, float* cs) {
  float rev = th * 0.15915494309189535f;
  rev -= floorf(rev);
  *sn = __builtin_amdgcn_sinf(rev);
  *cs = __builtin_amdgcn_cosf(rev);
}
// cos(th)+sin(th) = sqrt(2)*sin(th + pi/4): ONE transcendental.
__device__ __forceinline__ float fsc_sum(float th) {
  float rev = th * 0.15915494309189535f + 0.125f;
  rev -= floorf(rev);
  return 1.41421356237f * __builtin_amdgcn_sinf(rev);
}

// async global->LDS DMA, 16B/lane, LDS dest = uniform base + lane*16
__device__ __forceinline__ void dma16(const void* g, void* l) {
  __builtin_amdgcn_global_load_lds(
      (const __attribute__((address_space(1))) unsigned int*)g,
      (__attribute__((address_space(3))) unsigned int*)l, 16, 0, 0);
}

// Block per (bh, s-tile of 64). Emits:
//   Q  row-major [bh][s][128], scale QS2 folded (log2-domain scores)
//   K  swizzled  [bh][ktile64][d8 0..15][key 0..63] 16B units
//   V  swizzled  [bh][ktile64][k8 0..7][dv 0..63]  16B units
__global__ __launch_bounds__(256) void gen_qkv(
    const float* __restrict__ x,
    const float* __restrict__ wq, const float* __restrict__ bq,
    const float* __restrict__ phq,
    const float* __restrict__ wk, const float* __restrict__ bk,
    const float* __restrict__ phk,
    const float* __restrict__ wv, const float* __restrict__ bv,
    _Float16* __restrict__ Qd, _Float16* __restrict__ Kd, _Float16* __restrict__ Vtd)
{
  int stile = blockIdx.x & 31;
  int bh    = blockIdx.x >> 5;
  int b = bh >> 4, h = bh & 15;
  int t = threadIdx.x;
  int sl = t >> 2;                 // 0..63 (key/row within tile)
  int dq = (t & 3) << 4;           // 0,16,32,48
  int s  = stile * 64 + sl;

  __shared__ _Float16 Vl[64 * 65]; // transpose buffer, odd pitch

  const float* xr = x + (((size_t)b * SS + s) * HH + h) * DH + dq;
  float xv[16];
#pragma unroll
  for (int i = 0; i < 4; i++)
    *(f32x4v*)(&xv[i * 4]) = *(const f32x4v*)(xr + i * 4);

  int hd0 = h * DH + dq;
  float iwqv[16], vbq[16], vpq[16];
  float iwkv[16], vbk[16], vpk[16];
  float iwvv[16], vbv[16];
#pragma unroll
  for (int i = 0; i < 4; i++) {
    f32x4v w4, b4, p4;
    w4 = *(const f32x4v*)(wq + hd0 + i * 4);
    b4 = *(const f32x4v*)(bq + hd0 + i * 4);
    p4 = *(const f32x4v*)(phq + hd0 + i * 4);
#pragma unroll
    for (int j = 0; j < 4; j++) {
      iwqv[i*4+j] = __builtin_amdgcn_rcpf(1.f + fabsf(w4[j]));
      vbq[i*4+j] = b4[j]; vpq[i*4+j] = p4[j];
    }
    w4 = *(const f32x4v*)(wk + hd0 + i * 4);
    b4 = *(const f32x4v*)(bk + hd0 + i * 4);
    p4 = *(const f32x4v*)(phk + hd0 + i * 4);
#pragma unroll
    for (int j = 0; j < 4; j++) {
      iwkv[i*4+j] = __builtin_amdgcn_rcpf(1.f + fabsf(w4[j]));
      vbk[i*4+j] = b4[j]; vpk[i*4+j] = p4[j];
    }
    w4 = *(const f32x4v*)(wv + hd0 + i * 4);
    b4 = *(const f32x4v*)(bv + hd0 + i * 4);
#pragma unroll
    for (int j = 0; j < 4; j++) {
      iwvv[i*4+j] = __builtin_amdgcn_rcpf(1.f + fabsf(w4[j]));
      vbv[i*4+j] = b4[j];
    }
  }

  float tv = (float)s;
  _Float16 qc[16], qs[16], kc[16], ks[16];
#pragma unroll
  for (int i = 0; i < 16; i++) {
    int d = dq + i;
    {
      float th = xv[i] * iwqv[i] + vbq[i] + tv * vpq[i];
      float sn, cs; fsincos(th, &sn, &cs);
      qc[i] = (_Float16)(cs * QS2);
      qs[i] = (_Float16)(sn * QS2);
    }
    {
      float th = xv[i] * iwkv[i] + vbk[i] + tv * vpk[i];
      float sn, cs; fsincos(th, &sn, &cs);
      kc[i] = (_Float16)cs;
      ks[i] = (_Float16)sn;
    }
    {
      float th = xv[i] * iwvv[i] + vbv[i];
      Vl[d * 65 + sl] = (_Float16)fsc_sum(th);
    }
  }
  // Q row-major
  size_t qbase = ((size_t)bh * SS + s) * DQK;
#pragma unroll
  for (int i = 0; i < 2; i++) {
    *(half8_t*)(Qd + qbase + dq + i * 8)      = *(half8_t*)(&qc[i * 8]);
    *(half8_t*)(Qd + qbase + DH + dq + i * 8) = *(half8_t*)(&qs[i * 8]);
  }
  // K swizzled: cos dims d -> d8 = d/8; sin dims -> d8 = 8 + d/8
  {
    size_t ktb = ((size_t)bh * 32 + stile) * 8192;  // f16 base of 16KB tile
    int fo0 = (t & 3) * 2;
    *(half8_t*)(Kd + ktb + ((size_t)(fo0    ) * 64 + sl) * 8) = *(half8_t*)(&kc[0]);
    *(half8_t*)(Kd + ktb + ((size_t)(fo0 + 1) * 64 + sl) * 8) = *(half8_t*)(&kc[8]);
    *(half8_t*)(Kd + ktb + ((size_t)(fo0 + 8) * 64 + sl) * 8) = *(half8_t*)(&ks[0]);
    *(half8_t*)(Kd + ktb + ((size_t)(fo0 + 9) * 64 + sl) * 8) = *(half8_t*)(&ks[8]);
  }
  __syncthreads();
  // V swizzled: unit (k8, dv) = V[dv][keys k8*8..+7]; 2 units/thread, coalesced
#pragma unroll
  for (int i = 0; i < 2; i++) {
    int u = t * 2 + i;
    int dv = u & 63, ku = u >> 6;    // ku 0..7
    _Float16 tmp[8];
#pragma unroll
    for (int jj = 0; jj < 8; jj++) tmp[jj] = Vl[dv * 65 + ku * 8 + jj];
    *(half8_t*)(Vtd + (((size_t)bh * 32 + stile) * 8 + ku) * 512 + dv * 8) =
        *(half8_t*)tmp;
  }
}

// R8 = R7/R0 structure (2-buffer LDS dbuf + __syncthreads, LDS V, pitch-68
// epilogue, 3 blocks/CU) + VALU diet. Measured: VALUBusy 50% x 51us = 25.5us
// VALU-issue vs 13.7us MFMA floor -> flash is VALU-bound. Cuts:
//  (1) diagonal chunk PEELED: mask code (key/qrow/cmp/sel x16) no longer
//      compiled into the nch-1 mask-free chunks (provably exact: for
//      kt<nch-1, key <= q0-1 < qrow always).
//  (2) all hot-loop LDS/DMA addressing in 32-bit int with hoisted
//      thread-constant bases (was size_t -> v_lshl_add_u64 pairs on 16
//      ds_reads + 6 DMAs per chunk).
//  (3) cvt_pkrtz P-pack (8 ops, was 16 v_cvt_f16_f32).
__global__ __launch_bounds__(256) void flash_attn(
    const _Float16* __restrict__ Qd, const _Float16* __restrict__ Kd,
    const _Float16* __restrict__ Vtd,
    const float* __restrict__ wout, const float* __restrict__ bout,
    float* __restrict__ out)
{
  int qt = 31 - (blockIdx.x >> 5);   // LPT: heaviest first
  int bh = blockIdx.x & 31;          // XCD = bh % 8
  int b  = bh >> 4, hh = bh & 15;
  int nch = qt + 1;
  int q0 = qt * 64;
  int wave = threadIdx.x >> 6;
  int lane = threadIdx.x & 63;
  int lm = lane & 15, lq = lane >> 4;
  int qh = wave >> 1;
  int kh = wave & 1;

  __shared__ __align__(16) _Float16 KV[2][12288];   // per buf: K 16KB + V 8KB

  const _Float16* Kg = Kd + (size_t)bh * 32 * 8192;
  const _Float16* Vg = Vtd + (size_t)bh * 32 * 4096;

  int kslot = wave * 2048 + lane * 8;   // this thread's K-DMA src/dst offset
  int vslot = wave * 1024 + lane * 8;   // this thread's V-DMA src/dst offset

  {  // preload chunk 0 -> buf 0 (flies while Q frags load below)
#pragma unroll
    for (int i = 0; i < 4; i++)
      dma16(Kg + kslot + i * 512, &KV[0][kslot + i * 512]);
#pragma unroll
    for (int i = 0; i < 2; i++)
      dma16(Vg + vslot + i * 512, &KV[0][8192 + vslot + i * 512]);
  }

  // Q B-frags resident: B[n=q][k=c*32+lq*8+j]
  const _Float16* Qb = Qd + ((size_t)bh * SS + q0 + qh * 32) * DQK;
  half8_t aq[2][4];
#pragma unroll
  for (int qtl = 0; qtl < 2; qtl++)
#pragma unroll
    for (int c = 0; c < 4; c++)
      aq[qtl][c] = *(const half8_t*)(Qb + (qtl * 16 + lm) * DQK + c * 32 + lq * 8);

  f32x4_t o[4][2];   // [dv-tile][q-tile], element = O^T[dt*16+lq*4+r][qtl*16+lm]
  float l[2] = {0.f, 0.f};
#pragma unroll
  for (int dt = 0; dt < 4; dt++)
#pragma unroll
    for (int qtl = 0; qtl < 2; qtl++) o[dt][qtl] = (f32x4_t){0.f, 0.f, 0.f, 0.f};

  const f32x4_t cinit = (f32x4_t){-EBIAS, -EBIAS, -EBIAS, -EBIAS};

  // thread-constant LDS fragment bases (32-bit, hoisted out of the loop)
  int kbase = lq * 512 + (kh * 32 + lm) * 8;                      // K frag
  int vbase = (kh * 4 + (lq >> 1)) * 512 + lm * 8 + (lq & 1) * 4; // V frag

  // one chunk of QK^T -> softmax -> PV. maskit constant-folds per call site.
  auto CHUNK = [&](int bf, int k0, bool maskit) {
    const _Float16* lK = &KV[bf][0];
    const _Float16* lV = &KV[bf][8192];

    // S^T - EBIAS = K Q^T + (-EBIAS) : C-layout (key = lq*4+r, q = lm)
    f32x4_t cST[2][2];
    cST[0][0] = cST[0][1] = cST[1][0] = cST[1][1] = cinit;
    __builtin_amdgcn_s_setprio(1);
#pragma unroll
    for (int c = 0; c < 4; c++) {
      half8_t k0f = *(const half8_t*)(lK + kbase + c * 2048);
      half8_t k1f = *(const half8_t*)(lK + kbase + c * 2048 + 128);
      cST[0][0] = __builtin_amdgcn_mfma_f32_16x16x32_f16(k0f, aq[0][c], cST[0][0], 0, 0, 0);
      cST[0][1] = __builtin_amdgcn_mfma_f32_16x16x32_f16(k0f, aq[1][c], cST[0][1], 0, 0, 0);
      cST[1][0] = __builtin_amdgcn_mfma_f32_16x16x32_f16(k1f, aq[0][c], cST[1][0], 0, 0, 0);
      cST[1][1] = __builtin_amdgcn_mfma_f32_16x16x32_f16(k1f, aq[1][c], cST[1][1], 0, 0, 0);
    }
    __builtin_amdgcn_s_setprio(0);

    // p = 2^(s2) in-register; pack -> B-frags (B[n=q=lm][k=lq*4+i])
    half4_t pb[2][2];
#pragma unroll
    for (int ktl = 0; ktl < 2; ktl++)
#pragma unroll
      for (int qtl = 0; qtl < 2; qtl++) {
        float pf[4];
#pragma unroll
        for (int r = 0; r < 4; r++) {
          float sv = cST[ktl][qtl][r];
          if (maskit) {   // compiled ONLY into the peeled diagonal chunk
            int key  = k0 + kh * 32 + ktl * 16 + lq * 4 + r;
            int qrow = q0 + qh * 32 + qtl * 16 + lm;
            if (key > qrow) sv = -1e30f;
          }
          pf[r] = __builtin_exp2f(sv);
          l[qtl] += pf[r];
        }
        half4_t pv;
        *(fp16x2_t*)&pv       = __builtin_amdgcn_cvt_pkrtz(pf[0], pf[1]);
        *((fp16x2_t*)&pv + 1) = __builtin_amdgcn_cvt_pkrtz(pf[2], pf[3]);
        pb[ktl][qtl] = pv;
      }

    // O^T += V^T P^T : A = V^T frag (m=dv, k=key lq*4+i), 16 MFMA 16x16x16
    __builtin_amdgcn_s_setprio(1);
#pragma unroll
    for (int dt = 0; dt < 4; dt++)
#pragma unroll
      for (int kg = 0; kg < 2; kg++) {
        half4_t vf = *(const half4_t*)(lV + vbase + kg * 1024 + dt * 128);
        o[dt][0] = __builtin_amdgcn_mfma_f32_16x16x16f16(vf, pb[kg][0], o[dt][0], 0, 0, 0);
        o[dt][1] = __builtin_amdgcn_mfma_f32_16x16x16f16(vf, pb[kg][1], o[dt][1], 0, 0, 0);
      }
    __builtin_amdgcn_s_setprio(0);
  };

  // running DMA source pointers (advance by constant: no per-chunk 64b mul)
  const _Float16* kS = Kg + 8192 + kslot;   // chunk 1
  const _Float16* vS = Vg + 4096 + vslot;

  // main loop: chunks 0..nch-2, mask-free
  for (int kt = 0; kt < nch - 1; ++kt) {
    int bf = kt & 1;
    __syncthreads();   // drains DMA (vmcnt0 before barrier) + compute of kt-1
    {
      int nb = bf ^ 1;
#pragma unroll
      for (int i = 0; i < 4; i++)
        dma16(kS + i * 512, &KV[nb][kslot + i * 512]);
#pragma unroll
      for (int i = 0; i < 2; i++)
        dma16(vS + i * 512, &KV[nb][8192 + vslot + i * 512]);
      kS += 8192; vS += 4096;
    }
    CHUNK(bf, kt * 64, false);
  }
  // peeled diagonal chunk (the only one needing the causal mask)
  __syncthreads();
  CHUNK((nch - 1) & 1, (nch - 1) * 64, true);

  // reduce l over lq groups (keys): all lanes end with l for q = qtl*16+lm
#pragma unroll
  for (int qtl = 0; qtl < 2; qtl++) {
    l[qtl] += __shfl_xor(l[qtl], 16);
    l[qtl] += __shfl_xor(l[qtl], 32);
  }

  // combine kh halves + normalize via LDS overlaid on the idle KV buffer
  // (last chunk used buf (nch-1)&1, so buf nch&1 is free), then epilogue.
  int sc = nch & 1;
  float* Of = (float*)&KV[sc][0];        // [row][pitch 68], 17664 B < 24576 B
  float* Lf = Of + 64 * 68;
  __syncthreads();
  if (kh == 1) {
#pragma unroll
    for (int qtl = 0; qtl < 2; qtl++) {
      int row = qh * 32 + qtl * 16 + lm;
#pragma unroll
      for (int dt = 0; dt < 4; dt++)
#pragma unroll
        for (int r = 0; r < 4; r++)
          Of[row * 68 + dt * 16 + lq * 4 + r] = o[dt][qtl][r];
      if (lq == 0) Lf[row] = l[qtl];
    }
  }
  __syncthreads();
  if (kh == 0) {
#pragma unroll
    for (int qtl = 0; qtl < 2; qtl++) {
      int row = qh * 32 + qtl * 16 + lm;
      float rl = 1.f / (l[qtl] + Lf[row]);
#pragma unroll
      for (int dt = 0; dt < 4; dt++)
#pragma unroll
        for (int r = 0; r < 4; r++) {
          int idx = row * 68 + dt * 16 + lq * 4 + r;
          Of[idx] = (o[dt][qtl][r] + Of[idx]) * rl;
        }
    }
  }
  __syncthreads();
  {
    int dcol = hh * DH + lane;
    float iw = 1.f / (1.f + fabsf(wout[dcol]));
    float bo = bout[dcol];
#pragma unroll
    for (int rr = 0; rr < 16; rr++) {
      int row = wave * 16 + rr;
      float th = Of[row * 68 + lane] * iw + bo;
      out[((size_t)b * SS + q0 + row) * DD + dcol] = fsc_sum(th);
    }
  }
}

extern "C" void kernel_launch(void* const* d_in, const int* in_sizes, int n_in,
                              void* d_out, int out_size, void* d_ws, size_t ws_size,
                              hipStream_t stream) {
  (void)in_sizes; (void)n_in; (void)out_size; (void)ws_size;
  const float* x   = (const float*)d_in[0];
  const float* wq  = (const float*)d_in[1];
  const float* bq  = (const float*)d_in[2];
  const float* phq = (const float*)d_in[3];
  const float* wk  = (const float*)d_in[4];
  const float* bk  = (const float*)d_in[5];
  const float* phk = (const float*)d_in[6];
  const float* wv  = (const float*)d_in[7];
  const float* bv  = (const float*)d_in[8];
  const float* wo  = (const float*)d_in[9];
  const float* bo  = (const float*)d_in[10];

  _Float16* Qd  = (_Float16*)d_ws;
  _Float16* Kd  = Qd + (size_t)BB * HH * SS * DQK;
  _Float16* Vtd = Kd + (size_t)BB * HH * SS * DQK;

  gen_qkv<<<BB * HH * (SS / 64), 256, 0, stream>>>(
      x, wq, bq, phq, wk, bk, phk, wv, bv, Qd, Kd, Vtd);
  flash_attn<<<32 * 32, 256, 0, stream>>>(
      Qd, Kd, Vtd, wo, bo, (float*)d_out);
}